// Round 8
// baseline (930.083 us; speedup 1.0000x reference)
//
#include <hip/hip_runtime.h>

// Grouped GEMM (ragged rows over 8 experts) + dequant epilogue.
// R8 = R3 structure (BK=64, 128x128, 2-phase, gload_lds16 issue-early)
//    + supertile L2-locality remap (8mt x 11nt per-XCD supertiles)
//    + verified 8-chunk XOR bank swizzle (R5: 0 conflicts).

#define BK 64
#define NKSTEP 32   // 2048/64
#define KDIM 2048

typedef __attribute__((ext_vector_type(4))) float f32x4;
typedef __attribute__((ext_vector_type(4))) unsigned int u32x4;
using frag_ab = __attribute__((ext_vector_type(8))) short;
using frag_cd = __attribute__((ext_vector_type(4))) float;

__device__ __forceinline__ unsigned int pack_bf2(float x, float y) {
  unsigned int ux = __float_as_uint(x);
  unsigned int uy = __float_as_uint(y);
  ux += 0x7fffu + ((ux >> 16) & 1u);
  uy += 0x7fffu + ((uy >> 16) & 1u);
  return (ux >> 16) | (uy & 0xffff0000u);
}

__device__ __forceinline__ void gload_lds16(const void* g, void* lds) {
  __builtin_amdgcn_global_load_lds(
      (const __attribute__((address_space(1))) unsigned int*)g,
      (__attribute__((address_space(3))) unsigned int*)lds, 16, 0, 0);
}

// ---------------- convert pass: f32 -> bf16 into ws ----------------
__global__ __launch_bounds__(256)
void convert_kernel(const float* __restrict__ A, const float* __restrict__ B,
                    unsigned short* __restrict__ wa, unsigned short* __restrict__ wb) {
  constexpr long long NA = 16384LL * 2048;
  constexpr long long NB = 8LL * 5632 * 2048;
  constexpr long long NA8 = NA / 8;
  constexpr long long NTOT = (NA + NB) / 8;
  for (long long c = (long long)blockIdx.x * 256 + threadIdx.x; c < NTOT;
       c += (long long)gridDim.x * 256) {
    const float* src;
    unsigned short* dst;
    long long off;
    if (c < NA8) { src = A; dst = wa; off = c * 8; }
    else         { src = B; dst = wb; off = (c - NA8) * 8; }
    f32x4 v0 = *(const f32x4*)(src + off);
    f32x4 v1 = *(const f32x4*)(src + off + 4);
    u32x4 o;
    o[0] = pack_bf2(v0[0], v0[1]);
    o[1] = pack_bf2(v0[2], v0[3]);
    o[2] = pack_bf2(v1[0], v1[1]);
    o[3] = pack_bf2(v1[2], v1[3]);
    *(u32x4*)(dst + off) = o;
  }
}

// ---------------- bf16 grouped GEMM ----------------
// LDS per op per buf: [128 rows][64 k] bf16, swizzled:
//   phys 16B-chunk p of row r holds logical chunk p ^ (r&7)
// gload dest linear; global source pre-permuted; ds_read applies the XOR.
__global__ __launch_bounds__(256, 2)
void ggemm_s(const unsigned short* __restrict__ A,
             const unsigned short* __restrict__ B,
             const float* __restrict__ sa,
             const float* __restrict__ sb,
             const int* __restrict__ seg,
             float* __restrict__ C) {
  constexpr int M = 16384, N = 5632, E = 8;

  // ---- supertile L2 remap ----
  // per XCD: 704 blocks = 8 supertiles x (8 mt x 11 nt).
  // consecutive supertiles share the same 8-mt A band (4 MB, L2-resident).
  int bid = blockIdx.x;
  int xcd = bid & 7;
  int r = bid >> 3;            // [0,704)
  int st = r / 88, p = r % 88; // supertile, position
  int pm = p & 7, pn = p >> 3; // 8 mt x 11 nt inside supertile
  int smt = st >> 2, snt = st & 3;
  int mt = xcd * 16 + smt * 8 + pm;   // [0,128)
  int nt = snt * 11 + pn;             // [0,44)
  int m0 = mt * 128, n0 = nt * 128;

  int tid = threadIdx.x, lane = tid & 63, w = tid >> 6;
  int wr = (w >> 1) * 64, wc = (w & 1) * 64;   // 2x2 wave grid
  int l16 = lane & 15, lhi = lane >> 4;

  __shared__ unsigned short Asm[2][128 * 64];  // 32 KiB
  __shared__ unsigned short Bsm[2][128 * 64];  // 32 KiB

  // stage source coords (pre-permuted): lane -> row lane>>3, phys chunk lane&7,
  // fetch logical chunk (lane&7) ^ (lane>>3).
  int srow = lane >> 3;
  int scol = ((lane & 7) ^ srow) * 8;
  const unsigned short* gA = A + (size_t)(m0 + w * 32 + srow) * KDIM + scol;

  // ds_read swizzled offsets (shorts): row*64 + ((chunk ^ (row&7)) * 8)
  int c7 = l16 & 7;
  int x0 = (lhi ^ c7) * 8;          // ks=0: chunk lhi
  int x1 = ((4 | lhi) ^ c7) * 8;    // ks=1: chunk 4+lhi
  int offA[4], offB[4];
#pragma unroll
  for (int i = 0; i < 4; ++i) offA[i] = (wr + i * 16 + l16) * 64;
#pragma unroll
  for (int j = 0; j < 4; ++j) offB[j] = (wc + j * 16 + l16) * 64;

  for (int e = 0; e < E; ++e) {
    int rlo = max(m0, seg[e]);
    int rhi = min(m0 + 128, seg[e + 1]);
    if (rlo >= rhi) continue;
    const unsigned short* gB =
        B + (size_t)e * N * KDIM + (size_t)(n0 + w * 32 + srow) * KDIM + scol;

    frag_cd acc[4][4];
#pragma unroll
    for (int i = 0; i < 4; ++i)
#pragma unroll
      for (int j = 0; j < 4; ++j) acc[i][j] = (frag_cd){0.f, 0.f, 0.f, 0.f};

    auto stage = [&](int b, int kt) {
#pragma unroll
      for (int i = 0; i < 4; ++i) {
        gload_lds16(gA + (size_t)i * 8 * KDIM + kt * BK,
                    &Asm[b][(w * 32 + i * 8) * 64]);
        gload_lds16(gB + (size_t)i * 8 * KDIM + kt * BK,
                    &Bsm[b][(w * 32 + i * 8) * 64]);
      }
    };
    auto compute = [&](int b) {
      const unsigned short* pa = &Asm[b][0];
      const unsigned short* pb = &Bsm[b][0];
#pragma unroll
      for (int ks = 0; ks < 2; ++ks) {
        int x = ks ? x1 : x0;
        frag_ab af[4], bf[4];
#pragma unroll
        for (int i = 0; i < 4; ++i) af[i] = *(const frag_ab*)(pa + offA[i] + x);
#pragma unroll
        for (int j = 0; j < 4; ++j) bf[j] = *(const frag_ab*)(pb + offB[j] + x);
#pragma unroll
        for (int i = 0; i < 4; ++i)
#pragma unroll
          for (int j = 0; j < 4; ++j)
            acc[i][j] = __builtin_amdgcn_mfma_f32_16x16x32_bf16(
                af[i], bf[j], acc[i][j], 0, 0, 0);
      }
    };

    stage(0, 0);
    __syncthreads();
    for (int kt = 0; kt < NKSTEP; ++kt) {
      if (kt + 1 < NKSTEP) stage((kt + 1) & 1, kt + 1);  // issue-early
      compute(kt & 1);
      __syncthreads();
    }

    float sbe = sb[e];
#pragma unroll
    for (int i = 0; i < 4; ++i) {
#pragma unroll
      for (int rr = 0; rr < 4; ++rr) {
        int grow = m0 + wr + i * 16 + lhi * 4 + rr;
        if (grow >= rlo && grow < rhi) {
          float s = sa[grow] * sbe;
          float* Crow = C + (size_t)grow * N + n0 + wc;
#pragma unroll
          for (int j = 0; j < 4; ++j)
            Crow[j * 16 + l16] = acc[i][j][rr] * s;
        }
      }
    }
  }
}

extern "C" void kernel_launch(void* const* d_in, const int* in_sizes, int n_in,
                              void* d_out, int out_size, void* d_ws, size_t ws_size,
                              hipStream_t stream) {
  const float* a = (const float*)d_in[0];
  const float* b = (const float*)d_in[1];
  const float* sa = (const float*)d_in[2];
  const float* sb = (const float*)d_in[3];
  const int* seg = (const int*)d_in[4];
  float* out = (float*)d_out;

  constexpr size_t NA = 16384ULL * 2048;
  unsigned short* wa = (unsigned short*)d_ws;
  unsigned short* wb = wa + NA;

  hipLaunchKernelGGL(convert_kernel, dim3(2048), dim3(256), 0, stream, a, b, wa, wb);
  hipLaunchKernelGGL(ggemm_s, dim3(5632), dim3(256), 0, stream,
                     wa, wb, sa, sb, seg, out);
}

// Round 9
// 779.459 us; speedup vs baseline: 1.1932x; 1.1932x over previous
//
#include <hip/hip_runtime.h>

// Grouped GEMM (ragged rows over 8 experts) + dequant epilogue.
// R9 = R3 (best: BK=64, 128x128, 2-phase, gload_lds16 issue-early, T1 XCD
// swizzle, 2 blocks/CU) + the R5/R8-verified 8-chunk XOR bank swizzle.
// ONE change vs R3: LDS bank conflicts 1.46e8 -> ~0.

#define BK 64
#define NKSTEP 32   // 2048/64
#define KDIM 2048

typedef __attribute__((ext_vector_type(4))) float f32x4;
typedef __attribute__((ext_vector_type(4))) unsigned int u32x4;
using frag_ab = __attribute__((ext_vector_type(8))) short;
using frag_cd = __attribute__((ext_vector_type(4))) float;

__device__ __forceinline__ unsigned int pack_bf2(float x, float y) {
  unsigned int ux = __float_as_uint(x);
  unsigned int uy = __float_as_uint(y);
  ux += 0x7fffu + ((ux >> 16) & 1u);
  uy += 0x7fffu + ((uy >> 16) & 1u);
  return (ux >> 16) | (uy & 0xffff0000u);
}

__device__ __forceinline__ void gload_lds16(const void* g, void* lds) {
  __builtin_amdgcn_global_load_lds(
      (const __attribute__((address_space(1))) unsigned int*)g,
      (__attribute__((address_space(3))) unsigned int*)lds, 16, 0, 0);
}

// ---------------- convert pass: f32 -> bf16 into ws ----------------
__global__ __launch_bounds__(256)
void convert_kernel(const float* __restrict__ A, const float* __restrict__ B,
                    unsigned short* __restrict__ wa, unsigned short* __restrict__ wb) {
  constexpr long long NA = 16384LL * 2048;
  constexpr long long NB = 8LL * 5632 * 2048;
  constexpr long long NA8 = NA / 8;
  constexpr long long NTOT = (NA + NB) / 8;
  for (long long c = (long long)blockIdx.x * 256 + threadIdx.x; c < NTOT;
       c += (long long)gridDim.x * 256) {
    const float* src;
    unsigned short* dst;
    long long off;
    if (c < NA8) { src = A; dst = wa; off = c * 8; }
    else         { src = B; dst = wb; off = (c - NA8) * 8; }
    f32x4 v0 = *(const f32x4*)(src + off);
    f32x4 v1 = *(const f32x4*)(src + off + 4);
    u32x4 o;
    o[0] = pack_bf2(v0[0], v0[1]);
    o[1] = pack_bf2(v0[2], v0[3]);
    o[2] = pack_bf2(v1[0], v1[1]);
    o[3] = pack_bf2(v1[2], v1[3]);
    *(u32x4*)(dst + off) = o;
  }
}

// ---------------- bf16 grouped GEMM ----------------
// LDS per op per buf: [128 rows][64 k] bf16; swizzle: phys 16B-chunk p of
// row r holds logical chunk p ^ (r&7). gload dest linear; global source
// pre-permuted; ds_read applies the XOR (both-sides, rule 21).
__global__ __launch_bounds__(256, 2)
void ggemm_s(const unsigned short* __restrict__ A,
             const unsigned short* __restrict__ B,
             const float* __restrict__ sa,
             const float* __restrict__ sb,
             const int* __restrict__ seg,
             float* __restrict__ C) {
  constexpr int M = 16384, N = 5632, E = 8;
  constexpr int NTC = N / 128;          // 44
  const int nwg = (M / 128) * NTC;      // 5632, % 8 == 0

  // T1 XCD swizzle (R3's proven mapping)
  int bid = blockIdx.x;
  int sid = (bid & 7) * (nwg >> 3) + (bid >> 3);
  int mt = sid / NTC, nt = sid % NTC;
  int m0 = mt * 128, n0 = nt * 128;

  int tid = threadIdx.x, lane = tid & 63, w = tid >> 6;
  int wr = (w >> 1) * 64, wc = (w & 1) * 64;   // 2x2 wave grid
  int l16 = lane & 15, lhi = lane >> 4;

  __shared__ unsigned short Asm[2][128 * 64];  // 32 KiB
  __shared__ unsigned short Bsm[2][128 * 64];  // 32 KiB

  // stage source coords (pre-permuted): lane -> row lane>>3, phys chunk lane&7,
  // fetch logical chunk (lane&7) ^ (lane>>3).
  int srow = lane >> 3;
  int scol = ((lane & 7) ^ srow) * 8;
  const unsigned short* gA = A + (size_t)(m0 + w * 32 + srow) * KDIM + scol;

  // ds_read swizzled offsets (shorts): row*64 + ((chunk ^ (row&7)) * 8)
  int c7 = l16 & 7;
  int x0 = (lhi ^ c7) * 8;          // ks=0: chunk lhi
  int x1 = ((4 | lhi) ^ c7) * 8;    // ks=1: chunk 4+lhi
  int offA[4], offB[4];
#pragma unroll
  for (int i = 0; i < 4; ++i) offA[i] = (wr + i * 16 + l16) * 64;
#pragma unroll
  for (int j = 0; j < 4; ++j) offB[j] = (wc + j * 16 + l16) * 64;

  for (int e = 0; e < E; ++e) {
    int rlo = max(m0, seg[e]);
    int rhi = min(m0 + 128, seg[e + 1]);
    if (rlo >= rhi) continue;
    const unsigned short* gB =
        B + (size_t)e * N * KDIM + (size_t)(n0 + w * 32 + srow) * KDIM + scol;

    frag_cd acc[4][4];
#pragma unroll
    for (int i = 0; i < 4; ++i)
#pragma unroll
      for (int j = 0; j < 4; ++j) acc[i][j] = (frag_cd){0.f, 0.f, 0.f, 0.f};

    auto stage = [&](int b, int kt) {
#pragma unroll
      for (int i = 0; i < 4; ++i) {
        gload_lds16(gA + (size_t)i * 8 * KDIM + kt * BK,
                    &Asm[b][(w * 32 + i * 8) * 64]);
        gload_lds16(gB + (size_t)i * 8 * KDIM + kt * BK,
                    &Bsm[b][(w * 32 + i * 8) * 64]);
      }
    };
    auto compute = [&](int b) {
      const unsigned short* pa = &Asm[b][0];
      const unsigned short* pb = &Bsm[b][0];
#pragma unroll
      for (int ks = 0; ks < 2; ++ks) {
        int x = ks ? x1 : x0;
        frag_ab af[4], bf[4];
#pragma unroll
        for (int i = 0; i < 4; ++i) af[i] = *(const frag_ab*)(pa + offA[i] + x);
#pragma unroll
        for (int j = 0; j < 4; ++j) bf[j] = *(const frag_ab*)(pb + offB[j] + x);
#pragma unroll
        for (int i = 0; i < 4; ++i)
#pragma unroll
          for (int j = 0; j < 4; ++j)
            acc[i][j] = __builtin_amdgcn_mfma_f32_16x16x32_bf16(
                af[i], bf[j], acc[i][j], 0, 0, 0);
      }
    };

    stage(0, 0);
    __syncthreads();
    for (int kt = 0; kt < NKSTEP; ++kt) {
      if (kt + 1 < NKSTEP) stage((kt + 1) & 1, kt + 1);  // issue-early
      compute(kt & 1);
      __syncthreads();
    }

    float sbe = sb[e];
#pragma unroll
    for (int i = 0; i < 4; ++i) {
#pragma unroll
      for (int rr = 0; rr < 4; ++rr) {
        int grow = m0 + wr + i * 16 + lhi * 4 + rr;
        if (grow >= rlo && grow < rhi) {
          float s = sa[grow] * sbe;
          float* Crow = C + (size_t)grow * N + n0 + wc;
#pragma unroll
          for (int j = 0; j < 4; ++j)
            Crow[j * 16 + l16] = acc[i][j][rr] * s;
        }
      }
    }
  }
}

extern "C" void kernel_launch(void* const* d_in, const int* in_sizes, int n_in,
                              void* d_out, int out_size, void* d_ws, size_t ws_size,
                              hipStream_t stream) {
  const float* a = (const float*)d_in[0];
  const float* b = (const float*)d_in[1];
  const float* sa = (const float*)d_in[2];
  const float* sb = (const float*)d_in[3];
  const int* seg = (const int*)d_in[4];
  float* out = (float*)d_out;

  constexpr size_t NA = 16384ULL * 2048;
  unsigned short* wa = (unsigned short*)d_ws;
  unsigned short* wb = wa + NA;

  hipLaunchKernelGGL(convert_kernel, dim3(2048), dim3(256), 0, stream, a, b, wa, wb);
  hipLaunchKernelGGL(ggemm_s, dim3(5632), dim3(256), 0, stream,
                     wa, wb, sa, sb, seg, out);
}